// Round 1
// baseline (9515.586 us; speedup 1.0000x reference)
//
#include <hip/hip_runtime.h>
#include <hip/hip_cooperative_groups.h>

namespace cg = cooperative_groups;

#define T_STEPS 512
#define BATCH   32
#define DIM     1024
#define TBROWS  (T_STEPS * BATCH)   // 16384
#define BD      (BATCH * DIM)       // 32768

typedef __bf16 bf16x8 __attribute__((ext_vector_type(8)));
typedef float  f32x4  __attribute__((ext_vector_type(4)));
typedef unsigned short u16;
typedef u16 u16x4 __attribute__((ext_vector_type(4)));

__device__ __forceinline__ u16 f2bf(float f) {
    union { float f; unsigned u; } x; x.f = f;
    unsigned r = x.u + 0x7fffu + ((x.u >> 16) & 1u);   // round-to-nearest-even
    return (u16)(r >> 16);
}
__device__ __forceinline__ float bf2f(u16 b) {
    union { unsigned u; float f; } x; x.u = ((unsigned)b) << 16;
    return x.f;
}

// ---------------- Input projection: xp = x @ Wx^T + b, written to out[t+1] ----
#define PBM 128
#define PBN 128
#define PBK 32
#define ASTR 40   // u16 stride = 80 B (16B-aligned rows, bank-spread)

__global__ __launch_bounds__(256) void proj_kernel(
    const float* __restrict__ x, const float* __restrict__ Wx,
    const float* __restrict__ bias, float* __restrict__ out) {
    __shared__ u16 As[PBM * ASTR];
    __shared__ u16 Bs[PBN * ASTR];
    const int tid = threadIdx.x;
    const int l   = tid & 63;
    const int w   = tid >> 6;
    const int wr  = w >> 1, wc = w & 1;
    const int rowBase = blockIdx.y * PBM;
    const int colBase = blockIdx.x * PBN;
    const int lr  = l & 15;
    const int lk  = (l >> 4) * 8;

    f32x4 acc[4][4] = {};

    for (int kt = 0; kt < DIM / PBK; ++kt) {
        #pragma unroll
        for (int i = 0; i < 4; ++i) {
            int idx = tid + i * 256;
            int row = idx >> 3, kq = idx & 7;
            float4 va = *reinterpret_cast<const float4*>(
                x + (size_t)(rowBase + row) * DIM + kt * PBK + kq * 4);
            u16x4 sa = { f2bf(va.x), f2bf(va.y), f2bf(va.z), f2bf(va.w) };
            *reinterpret_cast<u16x4*>(&As[row * ASTR + kq * 4]) = sa;
            float4 vb = *reinterpret_cast<const float4*>(
                Wx + (size_t)(colBase + row) * DIM + kt * PBK + kq * 4);
            u16x4 sb = { f2bf(vb.x), f2bf(vb.y), f2bf(vb.z), f2bf(vb.w) };
            *reinterpret_cast<u16x4*>(&Bs[row * ASTR + kq * 4]) = sb;
        }
        __syncthreads();
        bf16x8 af[4], bff[4];
        #pragma unroll
        for (int mi = 0; mi < 4; ++mi)
            af[mi] = *reinterpret_cast<const bf16x8*>(&As[(wr * 64 + mi * 16 + lr) * ASTR + lk]);
        #pragma unroll
        for (int ni = 0; ni < 4; ++ni)
            bff[ni] = *reinterpret_cast<const bf16x8*>(&Bs[(wc * 64 + ni * 16 + lr) * ASTR + lk]);
        #pragma unroll
        for (int mi = 0; mi < 4; ++mi)
            #pragma unroll
            for (int ni = 0; ni < 4; ++ni)
                acc[mi][ni] = __builtin_amdgcn_mfma_f32_16x16x32_bf16(
                    af[mi], bff[ni], acc[mi][ni], 0, 0, 0);
        __syncthreads();
    }
    #pragma unroll
    for (int mi = 0; mi < 4; ++mi) {
        #pragma unroll
        for (int ni = 0; ni < 4; ++ni) {
            int col = colBase + wc * 64 + ni * 16 + lr;
            float bv = bias[col];
            #pragma unroll
            for (int j = 0; j < 4; ++j) {
                int row = rowBase + wr * 64 + mi * 16 + (l >> 4) * 4 + j;
                out[(size_t)(row + BATCH) * DIM + col] = acc[mi][ni][j] + bv;
            }
        }
    }
}

// ---------------- Recurrence: persistent cooperative kernel ------------------
#define NBLK 64
#define CPB  16   // output columns per block

__global__ __launch_bounds__(256) void rnn_kernel(
    const float* __restrict__ h0, const float* __restrict__ Wh,
    float* __restrict__ out, u16* __restrict__ hbuf) {
    cg::grid_group grid = cg::this_grid();
    __shared__ float red[4 * 32 * 17];
    const int tid = threadIdx.x;
    const int l   = tid & 63;
    const int w   = tid >> 6;
    const int g   = blockIdx.x;
    const int lr  = l & 15;
    const int lk8 = (l >> 4) * 8;

    // init: h0 -> out[0] (fp32) and hbuf[0] (bf16)
    for (int i = g * 256 + tid; i < BD; i += NBLK * 256) {
        float v = h0[i];
        out[i] = v;
        hbuf[i] = f2bf(v);
    }

    // W_h slice in registers, hi/lo bf16 split (2-term MFMA ~ fp32 matmul)
    bf16x8 whi[8], wlo[8];
    {
        const float* wp = Wh + (size_t)(g * CPB + lr) * DIM + w * 256 + lk8;
        #pragma unroll
        for (int s = 0; s < 8; ++s) {
            #pragma unroll
            for (int j = 0; j < 8; ++j) {
                float v = wp[s * 32 + j];
                u16 hb = f2bf(v);
                whi[s][j] = __builtin_bit_cast(__bf16, hb);
                wlo[s][j] = __builtin_bit_cast(__bf16, f2bf(v - bf2f(hb)));
            }
        }
    }

    __threadfence();
    grid.sync();

    for (int t = 0; t < T_STEPS; ++t) {
        const u16* hb = hbuf + (t & 1) * BD;
        u16*       hn = hbuf + ((t + 1) & 1) * BD;

        f32x4 acc[2] = {};
        #pragma unroll
        for (int s = 0; s < 8; ++s) {
            int k = w * 256 + s * 32 + lk8;
            bf16x8 a0 = *reinterpret_cast<const bf16x8*>(hb + (size_t)(lr) * DIM + k);
            bf16x8 a1 = *reinterpret_cast<const bf16x8*>(hb + (size_t)(16 + lr) * DIM + k);
            acc[0] = __builtin_amdgcn_mfma_f32_16x16x32_bf16(a0, whi[s], acc[0], 0, 0, 0);
            acc[1] = __builtin_amdgcn_mfma_f32_16x16x32_bf16(a1, whi[s], acc[1], 0, 0, 0);
            acc[0] = __builtin_amdgcn_mfma_f32_16x16x32_bf16(a0, wlo[s], acc[0], 0, 0, 0);
            acc[1] = __builtin_amdgcn_mfma_f32_16x16x32_bf16(a1, wlo[s], acc[1], 0, 0, 0);
        }
        #pragma unroll
        for (int m = 0; m < 2; ++m)
            #pragma unroll
            for (int j = 0; j < 4; ++j) {
                int b = m * 16 + (l >> 4) * 4 + j;
                red[(w * 32 + b) * 17 + lr] = acc[m][j];
            }
        __syncthreads();
        for (int o = tid; o < 512; o += 256) {
            int b = o >> 4, c = o & 15;
            float s0 = red[(0 * 32 + b) * 17 + c] + red[(1 * 32 + b) * 17 + c] +
                       red[(2 * 32 + b) * 17 + c] + red[(3 * 32 + b) * 17 + c];
            size_t oidx = (size_t)(t + 1) * BD + (size_t)b * DIM + g * CPB + c;
            float hv = tanhf(s0 + out[oidx]);      // out holds xp here
            out[oidx] = hv;
            hn[(size_t)b * DIM + g * CPB + c] = f2bf(hv);
        }
        __threadfence();
        grid.sync();
    }
}

extern "C" void kernel_launch(void* const* d_in, const int* in_sizes, int n_in,
                              void* d_out, int out_size, void* d_ws, size_t ws_size,
                              hipStream_t stream) {
    const float* x    = (const float*)d_in[0];
    const float* h0   = (const float*)d_in[1];
    const float* Wx   = (const float*)d_in[2];
    const float* Wh   = (const float*)d_in[3];
    const float* bias = (const float*)d_in[4];
    float* out = (float*)d_out;
    u16* hbuf  = (u16*)d_ws;   // 2 * 32768 * 2B = 128 KB ping-pong

    dim3 g1(DIM / PBN, TBROWS / PBM);   // (8, 128)
    proj_kernel<<<g1, 256, 0, stream>>>(x, Wx, bias, out);

    void* args[] = { (void*)&h0, (void*)&Wh, (void*)&out, (void*)&hbuf };
    hipLaunchCooperativeKernel((const void*)rnn_kernel, dim3(NBLK), dim3(256),
                               args, 0, stream);
}

// Round 2
// 3051.884 us; speedup vs baseline: 3.1179x; 3.1179x over previous
//
#include <hip/hip_runtime.h>

#define T_STEPS 512
#define BATCH   32
#define DIM     1024
#define TBROWS  (T_STEPS * BATCH)   // 16384
#define BD      (BATCH * DIM)       // 32768

typedef __bf16 bf16x8 __attribute__((ext_vector_type(8)));
typedef float  f32x4  __attribute__((ext_vector_type(4)));
typedef unsigned short u16;
typedef unsigned int   u32;
typedef u16 u16x4 __attribute__((ext_vector_type(4)));

__device__ __forceinline__ u16 f2bf(float f) {
    union { float f; u32 u; } x; x.f = f;
    u32 r = x.u + 0x7fffu + ((x.u >> 16) & 1u);   // round-to-nearest-even
    return (u16)(r >> 16);
}
__device__ __forceinline__ float bf2f(u16 b) {
    union { u32 u; float f; } x; x.u = ((u32)b) << 16;
    return x.f;
}

// device-coherent (bypass L1/L2, hit LLC) scalar dword store
__device__ __forceinline__ void store_cg_b32(u32* p, u32 v) {
    asm volatile("global_store_dword %0, %1, off sc0 sc1" :: "v"(p), "v"(v) : "memory");
}

// ---------------- Input projection: xp = x @ Wx^T + b  (3-term bf16 hi/lo) ---
#define PBM 128
#define PBN 128
#define PBK 32
#define ASTR 40   // u16 stride = 80 B

__global__ __launch_bounds__(256) void proj_kernel(
    const float* __restrict__ x, const float* __restrict__ Wx,
    const float* __restrict__ bias, float* __restrict__ out) {
    __shared__ u16 Ah[PBM * ASTR], Al[PBM * ASTR];
    __shared__ u16 Bh[PBN * ASTR], Bl[PBN * ASTR];
    const int tid = threadIdx.x;
    const int l   = tid & 63;
    const int w   = tid >> 6;
    const int wr  = w >> 1, wc = w & 1;
    const int rowBase = blockIdx.y * PBM;
    const int colBase = blockIdx.x * PBN;
    const int lr  = l & 15;
    const int lk  = (l >> 4) * 8;

    f32x4 acc[4][4] = {};

    for (int kt = 0; kt < DIM / PBK; ++kt) {
        #pragma unroll
        for (int i = 0; i < 4; ++i) {
            int idx = tid + i * 256;
            int row = idx >> 3, kq = idx & 7;
            float4 va = *reinterpret_cast<const float4*>(
                x + (size_t)(rowBase + row) * DIM + kt * PBK + kq * 4);
            u16x4 ha = { f2bf(va.x), f2bf(va.y), f2bf(va.z), f2bf(va.w) };
            u16x4 la = { f2bf(va.x - bf2f(ha.x)), f2bf(va.y - bf2f(ha.y)),
                         f2bf(va.z - bf2f(ha.z)), f2bf(va.w - bf2f(ha.w)) };
            *reinterpret_cast<u16x4*>(&Ah[row * ASTR + kq * 4]) = ha;
            *reinterpret_cast<u16x4*>(&Al[row * ASTR + kq * 4]) = la;
            float4 vb = *reinterpret_cast<const float4*>(
                Wx + (size_t)(colBase + row) * DIM + kt * PBK + kq * 4);
            u16x4 hb = { f2bf(vb.x), f2bf(vb.y), f2bf(vb.z), f2bf(vb.w) };
            u16x4 lb = { f2bf(vb.x - bf2f(hb.x)), f2bf(vb.y - bf2f(hb.y)),
                         f2bf(vb.z - bf2f(hb.z)), f2bf(vb.w - bf2f(hb.w)) };
            *reinterpret_cast<u16x4*>(&Bh[row * ASTR + kq * 4]) = hb;
            *reinterpret_cast<u16x4*>(&Bl[row * ASTR + kq * 4]) = lb;
        }
        __syncthreads();
        bf16x8 afh[4], afl[4], bfh[4], bfl[4];
        #pragma unroll
        for (int mi = 0; mi < 4; ++mi) {
            afh[mi] = *reinterpret_cast<const bf16x8*>(&Ah[(wr * 64 + mi * 16 + lr) * ASTR + lk]);
            afl[mi] = *reinterpret_cast<const bf16x8*>(&Al[(wr * 64 + mi * 16 + lr) * ASTR + lk]);
        }
        #pragma unroll
        for (int ni = 0; ni < 4; ++ni) {
            bfh[ni] = *reinterpret_cast<const bf16x8*>(&Bh[(wc * 64 + ni * 16 + lr) * ASTR + lk]);
            bfl[ni] = *reinterpret_cast<const bf16x8*>(&Bl[(wc * 64 + ni * 16 + lr) * ASTR + lk]);
        }
        #pragma unroll
        for (int mi = 0; mi < 4; ++mi)
            #pragma unroll
            for (int ni = 0; ni < 4; ++ni) {
                acc[mi][ni] = __builtin_amdgcn_mfma_f32_16x16x32_bf16(
                    afh[mi], bfh[ni], acc[mi][ni], 0, 0, 0);
                acc[mi][ni] = __builtin_amdgcn_mfma_f32_16x16x32_bf16(
                    afl[mi], bfh[ni], acc[mi][ni], 0, 0, 0);
                acc[mi][ni] = __builtin_amdgcn_mfma_f32_16x16x32_bf16(
                    afh[mi], bfl[ni], acc[mi][ni], 0, 0, 0);
            }
        __syncthreads();
    }
    #pragma unroll
    for (int mi = 0; mi < 4; ++mi) {
        #pragma unroll
        for (int ni = 0; ni < 4; ++ni) {
            int col = colBase + wc * 64 + ni * 16 + lr;
            float bv = bias[col];
            #pragma unroll
            for (int j = 0; j < 4; ++j) {
                int row = rowBase + wr * 64 + mi * 16 + (l >> 4) * 4 + j;
                out[(size_t)(row + BATCH) * DIM + col] = acc[mi][ni][j] + bv;
            }
        }
    }
}

// ---------------- Recurrence: persistent kernel, fence-free LLC exchange ----
#define NBLK 32
#define THR  512
#define CPB  32   // output columns per block

__device__ __forceinline__ void gbar(u32* bar, u32 target) {
    __syncthreads();   // emits s_waitcnt vmcnt(0) before s_barrier: all waves' stores drained
    if (threadIdx.x == 0) {
        __hip_atomic_fetch_add(bar, 1u, __ATOMIC_RELAXED, __HIP_MEMORY_SCOPE_AGENT);
        while (__hip_atomic_load(bar, __ATOMIC_RELAXED, __HIP_MEMORY_SCOPE_AGENT) < target) {}
    }
    __syncthreads();
}

__global__ __launch_bounds__(THR) void rnn_kernel(
    const float* __restrict__ h0, const float* __restrict__ Wh,
    float* __restrict__ out, u16* __restrict__ planes, u32* __restrict__ bar) {
    __shared__ float red[8 * 32 * 33];
    const int tid = threadIdx.x;
    const int l   = tid & 63;
    const int w   = tid >> 6;
    const int g   = blockIdx.x;
    const int lr  = l & 15;
    const int lk8 = (l >> 4) * 8;

    // W_h fragments in registers, hi/lo bf16 split. Wave w owns k in [w*128, w*128+128).
    bf16x8 wh[4][2], wl[4][2];
    #pragma unroll
    for (int s = 0; s < 4; ++s)
        #pragma unroll
        for (int ni = 0; ni < 2; ++ni) {
            const float* wp = Wh + (size_t)(g * CPB + ni * 16 + lr) * DIM + w * 128 + s * 32 + lk8;
            #pragma unroll
            for (int j = 0; j < 8; ++j) {
                float v = wp[j];
                u16 hb = f2bf(v);
                wh[s][ni][j] = __builtin_bit_cast(__bf16, hb);
                wl[s][ni][j] = __builtin_bit_cast(__bf16, f2bf(v - bf2f(hb)));
            }
        }

    // init: h0 -> out[0] (fp32) and planes parity 0 (hi/lo bf16), partitioned
    {
        int id  = g * THR + tid;          // 0..16383, one col-pair each
        int row = id >> 9, c2 = (id & 511) * 2;
        float v0 = h0[row * DIM + c2], v1 = h0[row * DIM + c2 + 1];
        out[row * DIM + c2] = v0; out[row * DIM + c2 + 1] = v1;
        u16 a = f2bf(v0), b = f2bf(v1);
        u32 hp = a | ((u32)b << 16);
        u32 lp = f2bf(v0 - bf2f(a)) | ((u32)f2bf(v1 - bf2f(b)) << 16);
        store_cg_b32((u32*)(planes + (size_t)row * DIM + c2), hp);
        store_cg_b32((u32*)(planes + (size_t)BD + (size_t)row * DIM + c2), lp);
    }
    u32 rnd = 1;
    gbar(bar, rnd * NBLK);

    const int erow = tid >> 4;                 // epilogue: row 0..31
    const int ec   = g * CPB + (tid & 15) * 2; // absolute col (pair)

    for (int t = 0; t < T_STEPS; ++t) {
        const u16* ph = planes + (size_t)(t & 1) * 2 * BD;
        const u16* pl = ph + BD;
        u16* qh = planes + (size_t)((t + 1) & 1) * 2 * BD;
        u16* ql = qh + BD;

        // xp operand for epilogue (own columns only) — issue early, used late
        size_t xidx = (size_t)(t + 1) * BD + (size_t)erow * DIM + ec;
        float xp0 = out[xidx], xp1 = out[xidx + 1];

        // h_t fragment loads: rows {lr, lr+16}, k = w*128 + s*32 + lk8, s=0..3
        const u16* b0h = ph + (size_t)lr * DIM + w * 128 + lk8;
        const u16* b1h = ph + (size_t)(lr + 16) * DIM + w * 128 + lk8;
        const u16* b0l = pl + (size_t)lr * DIM + w * 128 + lk8;
        const u16* b1l = pl + (size_t)(lr + 16) * DIM + w * 128 + lk8;
        bf16x8 a0h[4], a0l[4], a1h[4], a1l[4];
        asm volatile(
            "global_load_dwordx4 %0,  %16, off sc0 sc1\n\t"
            "global_load_dwordx4 %1,  %16, off offset:64 sc0 sc1\n\t"
            "global_load_dwordx4 %2,  %16, off offset:128 sc0 sc1\n\t"
            "global_load_dwordx4 %3,  %16, off offset:192 sc0 sc1\n\t"
            "global_load_dwordx4 %4,  %17, off sc0 sc1\n\t"
            "global_load_dwordx4 %5,  %17, off offset:64 sc0 sc1\n\t"
            "global_load_dwordx4 %6,  %17, off offset:128 sc0 sc1\n\t"
            "global_load_dwordx4 %7,  %17, off offset:192 sc0 sc1\n\t"
            "global_load_dwordx4 %8,  %18, off sc0 sc1\n\t"
            "global_load_dwordx4 %9,  %18, off offset:64 sc0 sc1\n\t"
            "global_load_dwordx4 %10, %18, off offset:128 sc0 sc1\n\t"
            "global_load_dwordx4 %11, %18, off offset:192 sc0 sc1\n\t"
            "global_load_dwordx4 %12, %19, off sc0 sc1\n\t"
            "global_load_dwordx4 %13, %19, off offset:64 sc0 sc1\n\t"
            "global_load_dwordx4 %14, %19, off offset:128 sc0 sc1\n\t"
            "global_load_dwordx4 %15, %19, off offset:192 sc0 sc1\n\t"
            "s_waitcnt vmcnt(0)"
            : "=&v"(a0h[0]), "=&v"(a0h[1]), "=&v"(a0h[2]), "=&v"(a0h[3]),
              "=&v"(a0l[0]), "=&v"(a0l[1]), "=&v"(a0l[2]), "=&v"(a0l[3]),
              "=&v"(a1h[0]), "=&v"(a1h[1]), "=&v"(a1h[2]), "=&v"(a1h[3]),
              "=&v"(a1l[0]), "=&v"(a1l[1]), "=&v"(a1l[2]), "=&v"(a1l[3])
            : "v"(b0h), "v"(b0l), "v"(b1h), "v"(b1l)
            : "memory");
        __builtin_amdgcn_sched_barrier(0);

        f32x4 acc[2][2] = {};
        #pragma unroll
        for (int s = 0; s < 4; ++s) {
            #pragma unroll
            for (int ni = 0; ni < 2; ++ni) {
                acc[0][ni] = __builtin_amdgcn_mfma_f32_16x16x32_bf16(a0h[s], wh[s][ni], acc[0][ni], 0, 0, 0);
                acc[0][ni] = __builtin_amdgcn_mfma_f32_16x16x32_bf16(a0l[s], wh[s][ni], acc[0][ni], 0, 0, 0);
                acc[0][ni] = __builtin_amdgcn_mfma_f32_16x16x32_bf16(a0h[s], wl[s][ni], acc[0][ni], 0, 0, 0);
                acc[1][ni] = __builtin_amdgcn_mfma_f32_16x16x32_bf16(a1h[s], wh[s][ni], acc[1][ni], 0, 0, 0);
                acc[1][ni] = __builtin_amdgcn_mfma_f32_16x16x32_bf16(a1l[s], wh[s][ni], acc[1][ni], 0, 0, 0);
                acc[1][ni] = __builtin_amdgcn_mfma_f32_16x16x32_bf16(a1h[s], wl[s][ni], acc[1][ni], 0, 0, 0);
            }
        }

        // split-k reduce across the 8 waves via LDS
        #pragma unroll
        for (int m = 0; m < 2; ++m)
            #pragma unroll
            for (int ni = 0; ni < 2; ++ni)
                #pragma unroll
                for (int j = 0; j < 4; ++j) {
                    int row = m * 16 + (l >> 4) * 4 + j;
                    int col = ni * 16 + lr;
                    red[(w * 32 + row) * 33 + col] = acc[m][ni][j];
                }
        __syncthreads();
        float s0 = 0.f, s1 = 0.f;
        int cc = (tid & 15) * 2;
        #pragma unroll
        for (int ww = 0; ww < 8; ++ww) {
            s0 += red[(ww * 32 + erow) * 33 + cc];
            s1 += red[(ww * 32 + erow) * 33 + cc + 1];
        }
        float hv0 = tanhf(s0 + xp0);
        float hv1 = tanhf(s1 + xp1);
        out[xidx]     = hv0;   // normal store: never read cross-block
        out[xidx + 1] = hv1;
        u16 a = f2bf(hv0), b = f2bf(hv1);
        u32 hp = a | ((u32)b << 16);
        u32 lp = f2bf(hv0 - bf2f(a)) | ((u32)f2bf(hv1 - bf2f(b)) << 16);
        store_cg_b32((u32*)(qh + (size_t)erow * DIM + ec), hp);
        store_cg_b32((u32*)(ql + (size_t)erow * DIM + ec), lp);

        ++rnd;
        gbar(bar, rnd * NBLK);
    }
}

extern "C" void kernel_launch(void* const* d_in, const int* in_sizes, int n_in,
                              void* d_out, int out_size, void* d_ws, size_t ws_size,
                              hipStream_t stream) {
    const float* x    = (const float*)d_in[0];
    const float* h0   = (const float*)d_in[1];
    const float* Wx   = (const float*)d_in[2];
    const float* Wh   = (const float*)d_in[3];
    const float* bias = (const float*)d_in[4];
    float* out = (float*)d_out;

    u32* bar    = (u32*)d_ws;
    u16* planes = (u16*)((char*)d_ws + 256);   // 2 parities x {hi,lo} x [32][1024] u16 = 256 KB

    hipMemsetAsync(d_ws, 0, 256, stream);

    dim3 g1(DIM / PBN, TBROWS / PBM);   // (8, 128)
    proj_kernel<<<g1, 256, 0, stream>>>(x, Wx, bias, out);

    rnn_kernel<<<dim3(NBLK), dim3(THR), 0, stream>>>(h0, Wh, out, planes, bar);
}